// Round 7
// baseline (1945.770 us; speedup 1.0000x reference)
//
#include <hip/hip_runtime.h>

// Multiscale Residual VQ (VAR-style), MI355X gfx950.
// Round 7: VGPR-route staging (round-5: loads hoist/overlap across waves)
// + fragment-slot LDS layout (round-6: ds_write/ds_read at lane*16 -> 2-way,
// conflict-free). Round-6's global_load_lds DMA couldn't be hoisted above the
// barrier (vmcnt(0) drain serialized latency into all 16 K-iters -> 162us);
// round-5's layout was 8-way conflicted (137us). This combines the fixes.
// All MFMA dots bit-identical to rounds 4-6 -> zero argmin-flip risk.

#define ND 512
#define NCB 4096

typedef _Float16 half8v __attribute__((ext_vector_type(8)));
typedef float floatx4 __attribute__((ext_vector_type(4)));

struct HL { _Float16 h, l; };

__device__ __forceinline__ HL split2(float v) {
    HL r;
    r.h = (_Float16)v;
    r.l = (_Float16)((v - (float)r.h) * 4096.0f);
    return r;
}

__device__ __forceinline__ unsigned long long pack_dist(float d, int n) {
    unsigned u = __float_as_uint(d);
    u = (u & 0x80000000u) ? ~u : (u | 0x80000000u);   // monotone total order
    return ((unsigned long long)u << 32) | (unsigned)n; // tie -> lowest idx
}

// e_sq[c] = sum_d embed[c,d]^2, fp64 accumulate
__global__ __launch_bounds__(256) void k_esq(const float* __restrict__ embed,
                                             float* __restrict__ esq) {
    int c = blockIdx.x * 4 + (threadIdx.x >> 6);
    int lane = threadIdx.x & 63;
    const float* row = embed + (size_t)c * ND;
    double acc = 0.0;
#pragma unroll
    for (int i = 0; i < ND / 64; ++i) {
        float v = row[lane + i * 64];
        acc += (double)v * (double)v;
    }
#pragma unroll
    for (int off = 32; off > 0; off >>= 1) acc += __shfl_down(acc, off, 64);
    if (lane == 0) esq[c] = (float)acc;
}

__global__ __launch_bounds__(256) void k_copy(const float* __restrict__ src,
                                              float* __restrict__ dst) {
    int gid = blockIdx.x * 256 + threadIdx.x;
    ((float4*)dst)[gid] = ((const float4*)src)[gid];
}

// embed -> ehi/elo row-major halves (4096x512)
__global__ __launch_bounds__(256) void k_split_embed(const float* __restrict__ embed,
        _Float16* __restrict__ eh, _Float16* __restrict__ el) {
    int gid = blockIdx.x * 256 + threadIdx.x;       // 524288 float4s
    float4 v = ((const float4*)embed)[gid];
    HL a = split2(v.x), b = split2(v.y), c = split2(v.z), d = split2(v.w);
    _Float16* ph = eh + (size_t)gid * 4;
    _Float16* pl = el + (size_t)gid * 4;
    ph[0] = a.h; ph[1] = b.h; ph[2] = c.h; ph[3] = d.h;
    pl[0] = a.l; pl[1] = b.l; pl[2] = c.l; pl[3] = d.l;
}

// Wt2[kp][tap*512+dout][din] hi/lo from pw[kp][dout][din][tap]
__global__ __launch_bounds__(256) void k_split_w(const float* __restrict__ pw,
        _Float16* __restrict__ wh, _Float16* __restrict__ wl) {
    int gid = blockIdx.x * 256 + threadIdx.x;       // 4*1536*512
    int din = gid & 511;
    int nn = (gid >> 9) % 1536;
    int kp = gid / (512 * 1536);
    int tap = nn >> 9;
    int dout = nn & 511;
    float v = pw[(((size_t)(kp * 512 + dout) * 512) + din) * 3 + tap];
    HL r = split2(v);
    wh[gid] = r.h;
    wl[gid] = r.l;
}

// z[b,j,d] = block mean of residual (fp64 acc) -> split zh/zl; also inits minbuf
__global__ __launch_bounds__(256) void k_zmean(const float* __restrict__ resid,
        _Float16* __restrict__ zh, _Float16* __restrict__ zl,
        unsigned long long* __restrict__ minbuf, int s, int lg) {
    int gid = blockIdx.x * 256 + threadIdx.x;       // 16*s*512 threads
    int M = 16 * s;
    if (gid < M) minbuf[gid] = ~0ull;
    int d = gid & 511;
    int j = (gid >> 9) & (s - 1);
    int b = gid >> (9 + lg);
    int r = 512 >> lg;
    const float* p = resid + ((size_t)((b << 9) + (j << (9 - lg))) << 9) + d;
    double acc = 0.0;
#pragma unroll 4
    for (int m = 0; m < r; ++m) acc += (double)p[(size_t)m * ND];
    float v = (float)(acc * (1.0 / (double)r));
    HL hl = split2(v);
    zh[gid] = hl.h;
    zl[gid] = hl.l;
}

// h split: hh/hl[b*512+t][d] = split(lerp of embed rows per half-pixel upsample)
__global__ __launch_bounds__(256) void k_hsplit(const unsigned long long* __restrict__ minbuf,
        const float* __restrict__ embed, _Float16* __restrict__ hh,
        _Float16* __restrict__ hl, int s, float scale) {
    int gid = blockIdx.x * 256 + threadIdx.x;       // 524288: one 8-elem chunk
    int d8 = (gid & 63) << 3;
    int m = gid >> 6;
    int b = m >> 9, t = m & 511;
    float u = ((float)t + 0.5f) * scale - 0.5f;
    float fl = floorf(u);
    float w = u - fl;
    int i0 = (int)fl, i1 = i0 + 1;
    i0 = min(max(i0, 0), s - 1);
    i1 = min(max(i1, 0), s - 1);
    int c0 = (int)(unsigned)minbuf[b * s + i0];
    int c1 = (int)(unsigned)minbuf[b * s + i1];
    const float* p0 = embed + (size_t)c0 * 512 + d8;
    const float* p1 = embed + (size_t)c1 * 512 + d8;
    float om = 1.0f - w;
    half8v vh, vl;
#pragma unroll
    for (int q = 0; q < 8; ++q) {
        HL r = split2(om * p0[q] + w * p1[q]);
        vh[q] = r.h; vl[q] = r.l;
    }
    *(half8v*)(hh + (size_t)m * 512 + d8) = vh;
    *(half8v*)(hl + (size_t)m * 512 + d8) = vl;
}

// ---------------- dist: block 128m x 128n, 4 waves (2x2) each 64x64 ----------------
// LDS: fragment slots [frag = mt*2+half][slotlane*8], 16B per slotlane.
__global__ __launch_bounds__(256, 2) void k_dist_mfma(const _Float16* __restrict__ zh,
        const _Float16* __restrict__ zl, const _Float16* __restrict__ eh,
        const _Float16* __restrict__ el, const float* __restrict__ esq,
        unsigned long long* __restrict__ minbuf, int M) {
    __shared__ _Float16 Asl[16][512];
    __shared__ _Float16 Bsl[16][512];
    __shared__ unsigned long long packs[128][2];
    int tid = threadIdx.x;
    int lane = tid & 63, wave = tid >> 6;
    int wm = wave >> 1, wn = wave & 1;
    int quad = lane >> 4, l15 = lane & 15;
    int m0 = blockIdx.x * 128, n0 = blockIdx.y * 128;

    floatx4 acch[4][4], accx[4][4];
#pragma unroll
    for (int i = 0; i < 4; ++i)
#pragma unroll
        for (int j = 0; j < 4; ++j)
#pragma unroll
            for (int r = 0; r < 4; ++r) { acch[i][j][r] = 0.f; accx[i][j][r] = 0.f; }

    for (int kc = 0; kc < 16; ++kc) {
        int kb = kc * 32;
        int4 av[4], bv[4];
#pragma unroll
        for (int ch = 0; ch < 4; ++ch) {
            int g = tid + ch * 256;
            int fr = g >> 6, sl = g & 63;
            int mt = fr >> 1, half = fr & 1;
            int ko = kb + (sl >> 4) * 8;
            int arow = m0 + mt * 16 + (sl & 15); if (arow >= M) arow = M - 1;
            av[ch] = *(const int4*)((half ? zl : zh) + (size_t)arow * 512 + ko);
            int brow = n0 + mt * 16 + (sl & 15);
            bv[ch] = *(const int4*)((half ? el : eh) + (size_t)brow * 512 + ko);
        }
        __syncthreads();   // previous tile's fragment reads complete
#pragma unroll
        for (int ch = 0; ch < 4; ++ch) {
            int g = tid + ch * 256;
            int fr = g >> 6, sl = g & 63;
            *(int4*)&Asl[fr][sl * 8] = av[ch];
            *(int4*)&Bsl[fr][sl * 8] = bv[ch];
        }
        __syncthreads();
        half8v afh[4], afl[4], bfh[4], bfl[4];
#pragma unroll
        for (int t = 0; t < 4; ++t) {
            afh[t] = *(const half8v*)&Asl[(wm * 4 + t) * 2 + 0][lane * 8];
            afl[t] = *(const half8v*)&Asl[(wm * 4 + t) * 2 + 1][lane * 8];
            bfh[t] = *(const half8v*)&Bsl[(wn * 4 + t) * 2 + 0][lane * 8];
            bfl[t] = *(const half8v*)&Bsl[(wn * 4 + t) * 2 + 1][lane * 8];
        }
#pragma unroll
        for (int tm = 0; tm < 4; ++tm)
#pragma unroll
            for (int tn = 0; tn < 4; ++tn) {
                acch[tm][tn] = __builtin_amdgcn_mfma_f32_16x16x32_f16(afh[tm], bfh[tn], acch[tm][tn], 0, 0, 0);
                accx[tm][tn] = __builtin_amdgcn_mfma_f32_16x16x32_f16(afh[tm], bfl[tn], accx[tm][tn], 0, 0, 0);
                accx[tm][tn] = __builtin_amdgcn_mfma_f32_16x16x32_f16(afl[tm], bfh[tn], accx[tm][tn], 0, 0, 0);
            }
    }
    float es[4];
#pragma unroll
    for (int tn = 0; tn < 4; ++tn) es[tn] = esq[n0 + wn * 64 + tn * 16 + l15];
#pragma unroll
    for (int tm = 0; tm < 4; ++tm)
#pragma unroll
        for (int reg = 0; reg < 4; ++reg) {
            unsigned long long best = ~0ull;
#pragma unroll
            for (int tn = 0; tn < 4; ++tn) {
                float dot = acch[tm][tn][reg] + accx[tm][tn][reg] * (1.0f / 4096.0f);
                int n = n0 + wn * 64 + tn * 16 + l15;
                float dd = fmaf(-2.f, dot, es[tn]);
                unsigned long long p = pack_dist(dd, n);
                best = p < best ? p : best;
            }
#pragma unroll
            for (int off = 1; off < 16; off <<= 1) {
                unsigned long long q = __shfl_xor(best, off, 64);
                best = q < best ? q : best;
            }
            if (l15 == 0) packs[wm * 64 + tm * 16 + quad * 4 + reg][wn] = best;
        }
    __syncthreads();
    if (tid < 128 && m0 + tid < M) {
        unsigned long long b0 = packs[tid][0], b1 = packs[tid][1];
        atomicMin(&minbuf[m0 + tid], b0 < b1 ? b0 : b1);
    }
}

// ---------------- phi: u[m][tap*512+dout] = (W_tap q_m)[dout] ----------------
__global__ __launch_bounds__(256, 2) void k_phi(const _Float16* __restrict__ eh,
        const _Float16* __restrict__ el, const _Float16* __restrict__ wh,
        const _Float16* __restrict__ wl, const unsigned long long* __restrict__ minbuf,
        float* __restrict__ u, int M) {
    __shared__ _Float16 Asl[16][512];
    __shared__ _Float16 Bsl[16][512];
    __shared__ int idxs[128];
    int tid = threadIdx.x;
    int lane = tid & 63, wave = tid >> 6;
    int wm = wave >> 1, wn = wave & 1;
    int quad = lane >> 4, l15 = lane & 15;
    int m0 = blockIdx.x * 128, n0 = blockIdx.y * 128;
    if (tid < 128) {
        int m = m0 + tid; if (m >= M) m = M - 1;
        idxs[tid] = (int)(unsigned)minbuf[m];
    }
    floatx4 acch[4][4], accx[4][4];
#pragma unroll
    for (int i = 0; i < 4; ++i)
#pragma unroll
        for (int j = 0; j < 4; ++j)
#pragma unroll
            for (int r = 0; r < 4; ++r) { acch[i][j][r] = 0.f; accx[i][j][r] = 0.f; }
    __syncthreads();
    for (int kc = 0; kc < 16; ++kc) {
        int kb = kc * 32;
        int4 av[4], bv[4];
#pragma unroll
        for (int ch = 0; ch < 4; ++ch) {
            int g = tid + ch * 256;
            int fr = g >> 6, sl = g & 63;
            int mt = fr >> 1, half = fr & 1;
            int ko = kb + (sl >> 4) * 8;
            int code = idxs[mt * 16 + (sl & 15)];
            av[ch] = *(const int4*)((half ? el : eh) + (size_t)code * 512 + ko);
            int brow = n0 + mt * 16 + (sl & 15);
            bv[ch] = *(const int4*)((half ? wl : wh) + (size_t)brow * 512 + ko);
        }
        __syncthreads();
#pragma unroll
        for (int ch = 0; ch < 4; ++ch) {
            int g = tid + ch * 256;
            int fr = g >> 6, sl = g & 63;
            *(int4*)&Asl[fr][sl * 8] = av[ch];
            *(int4*)&Bsl[fr][sl * 8] = bv[ch];
        }
        __syncthreads();
        half8v afh[4], afl[4], bfh[4], bfl[4];
#pragma unroll
        for (int t = 0; t < 4; ++t) {
            afh[t] = *(const half8v*)&Asl[(wm * 4 + t) * 2 + 0][lane * 8];
            afl[t] = *(const half8v*)&Asl[(wm * 4 + t) * 2 + 1][lane * 8];
            bfh[t] = *(const half8v*)&Bsl[(wn * 4 + t) * 2 + 0][lane * 8];
            bfl[t] = *(const half8v*)&Bsl[(wn * 4 + t) * 2 + 1][lane * 8];
        }
#pragma unroll
        for (int tm = 0; tm < 4; ++tm)
#pragma unroll
            for (int tn = 0; tn < 4; ++tn) {
                acch[tm][tn] = __builtin_amdgcn_mfma_f32_16x16x32_f16(afh[tm], bfh[tn], acch[tm][tn], 0, 0, 0);
                accx[tm][tn] = __builtin_amdgcn_mfma_f32_16x16x32_f16(afh[tm], bfl[tn], accx[tm][tn], 0, 0, 0);
                accx[tm][tn] = __builtin_amdgcn_mfma_f32_16x16x32_f16(afl[tm], bfh[tn], accx[tm][tn], 0, 0, 0);
            }
    }
#pragma unroll
    for (int tm = 0; tm < 4; ++tm)
#pragma unroll
        for (int reg = 0; reg < 4; ++reg) {
            int m = m0 + wm * 64 + tm * 16 + quad * 4 + reg;
            if (m < M) {
#pragma unroll
                for (int tn = 0; tn < 4; ++tn) {
                    int n = n0 + wn * 64 + tn * 16 + l15;
                    u[(size_t)m * 1536 + n] = acch[tm][tn][reg] + accx[tm][tn][reg] * (1.0f / 4096.0f);
                }
            }
        }
}

// combine (s<=128): resid -= 0.5*h + 0.5*(conv+bias); conv[t] = sum_tap lerp of u
__global__ __launch_bounds__(256) void k_combine(const float* __restrict__ u,
        const float* __restrict__ embed, const unsigned long long* __restrict__ minbuf,
        const float* __restrict__ bias, float* __restrict__ resid, int s, float scale) {
    int tid = threadIdx.x;
    int m = blockIdx.x * 2 + (tid >> 7);
    int d4 = (tid & 127) << 2;
    int b = m >> 9, t = m & 511;
    int bs = b * s;
    float4 bi = *(const float4*)(bias + d4);
    float uu = ((float)t + 0.5f) * scale - 0.5f;
    float fl = floorf(uu);
    float w = uu - fl;
    int i0 = (int)fl, i1 = i0 + 1;
    i0 = min(max(i0, 0), s - 1);
    i1 = min(max(i1, 0), s - 1);
    int c0 = (int)(unsigned)minbuf[bs + i0];
    int c1 = (int)(unsigned)minbuf[bs + i1];
    float4 e0 = *(const float4*)(embed + (size_t)c0 * 512 + d4);
    float4 e1 = *(const float4*)(embed + (size_t)c1 * 512 + d4);
    float om = 1.0f - w;
    float4 h4;
    h4.x = om * e0.x + w * e1.x; h4.y = om * e0.y + w * e1.y;
    h4.z = om * e0.z + w * e1.z; h4.w = om * e0.w + w * e1.w;
    float4 conv = make_float4(0.f, 0.f, 0.f, 0.f);
#pragma unroll
    for (int tap = 0; tap < 3; ++tap) {
        int tt = t + tap - 1;
        if (tt >= 0 && tt < 512) {
            float uu2 = ((float)tt + 0.5f) * scale - 0.5f;
            float fl2 = floorf(uu2);
            float w2 = uu2 - fl2;
            int j0 = (int)fl2, j1 = j0 + 1;
            j0 = min(max(j0, 0), s - 1);
            j1 = min(max(j1, 0), s - 1);
            float4 a4 = *(const float4*)(u + (size_t)(bs + j0) * 1536 + tap * 512 + d4);
            float4 b4 = *(const float4*)(u + (size_t)(bs + j1) * 1536 + tap * 512 + d4);
            float ow = 1.0f - w2;
            conv.x += ow * a4.x + w2 * b4.x;
            conv.y += ow * a4.y + w2 * b4.y;
            conv.z += ow * a4.z + w2 * b4.z;
            conv.w += ow * a4.w + w2 * b4.w;
        }
    }
    size_t off = (size_t)m * 512 + d4;
    float4 rv = *(float4*)(resid + off);
    rv.x -= 0.5f * h4.x + 0.5f * (conv.x + bi.x);
    rv.y -= 0.5f * h4.y + 0.5f * (conv.y + bi.y);
    rv.z -= 0.5f * h4.z + 0.5f * (conv.z + bi.z);
    rv.w -= 0.5f * h4.w + 0.5f * (conv.w + bi.w);
    *(float4*)(resid + off) = rv;
}

// direct conv (s in {256,512}): A = hsplit rows shifted by tap, B = Wt2.
// epilogue: resid -= 0.5*h + 0.5*(conv+bias). grid(64, 4)
__global__ __launch_bounds__(256, 2) void k_conv(const _Float16* __restrict__ hh,
        const _Float16* __restrict__ hl, const _Float16* __restrict__ wh,
        const _Float16* __restrict__ wl, const float* __restrict__ bias,
        float* __restrict__ resid) {
    __shared__ _Float16 Asl[16][512];
    __shared__ _Float16 Bsl[16][512];
    int tid = threadIdx.x;
    int lane = tid & 63, wave = tid >> 6;
    int wm = wave >> 1, wn = wave & 1;
    int quad = lane >> 4, l15 = lane & 15;
    int m0 = blockIdx.x * 128, n0 = blockIdx.y * 128;
    int bb = m0 >> 9, t0 = m0 & 511;

    floatx4 acch[4][4], accx[4][4];
#pragma unroll
    for (int i = 0; i < 4; ++i)
#pragma unroll
        for (int j = 0; j < 4; ++j)
#pragma unroll
            for (int r = 0; r < 4; ++r) { acch[i][j][r] = 0.f; accx[i][j][r] = 0.f; }

    for (int kc = 0; kc < 48; ++kc) {
        int tap = kc >> 4;
        int kbd = (kc & 15) * 32;
        int4 av[4], bv[4];
#pragma unroll
        for (int ch = 0; ch < 4; ++ch) {
            int g = tid + ch * 256;
            int fr = g >> 6, sl = g & 63;
            int mt = fr >> 1, half = fr & 1;
            int ko = kbd + (sl >> 4) * 8;
            int tt = t0 + mt * 16 + (sl & 15) + tap - 1;
            int4 v = make_int4(0, 0, 0, 0);
            if ((unsigned)tt < 512u)
                v = *(const int4*)((half ? hl : hh) + ((size_t)((bb << 9) + tt)) * 512 + ko);
            av[ch] = v;
            int brow = tap * 512 + n0 + mt * 16 + (sl & 15);
            bv[ch] = *(const int4*)((half ? wl : wh) + (size_t)brow * 512 + ko);
        }
        __syncthreads();
#pragma unroll
        for (int ch = 0; ch < 4; ++ch) {
            int g = tid + ch * 256;
            int fr = g >> 6, sl = g & 63;
            *(int4*)&Asl[fr][sl * 8] = av[ch];
            *(int4*)&Bsl[fr][sl * 8] = bv[ch];
        }
        __syncthreads();
        half8v afh[4], afl[4], bfh[4], bfl[4];
#pragma unroll
        for (int t = 0; t < 4; ++t) {
            afh[t] = *(const half8v*)&Asl[(wm * 4 + t) * 2 + 0][lane * 8];
            afl[t] = *(const half8v*)&Asl[(wm * 4 + t) * 2 + 1][lane * 8];
            bfh[t] = *(const half8v*)&Bsl[(wn * 4 + t) * 2 + 0][lane * 8];
            bfl[t] = *(const half8v*)&Bsl[(wn * 4 + t) * 2 + 1][lane * 8];
        }
#pragma unroll
        for (int tm = 0; tm < 4; ++tm)
#pragma unroll
            for (int tn = 0; tn < 4; ++tn) {
                acch[tm][tn] = __builtin_amdgcn_mfma_f32_16x16x32_f16(afh[tm], bfh[tn], acch[tm][tn], 0, 0, 0);
                accx[tm][tn] = __builtin_amdgcn_mfma_f32_16x16x32_f16(afh[tm], bfl[tn], accx[tm][tn], 0, 0, 0);
                accx[tm][tn] = __builtin_amdgcn_mfma_f32_16x16x32_f16(afl[tm], bfh[tn], accx[tm][tn], 0, 0, 0);
            }
    }
#pragma unroll
    for (int tm = 0; tm < 4; ++tm)
#pragma unroll
        for (int reg = 0; reg < 4; ++reg) {
            int m = m0 + wm * 64 + tm * 16 + quad * 4 + reg;
#pragma unroll
            for (int tn = 0; tn < 4; ++tn) {
                int n = n0 + wn * 64 + tn * 16 + l15;
                size_t off = (size_t)m * 512 + n;
                float hval = (float)hh[off] + (float)hl[off] * (1.0f / 4096.0f);
                float val = acch[tm][tn][reg] + accx[tm][tn][reg] * (1.0f / 4096.0f);
                resid[off] -= 0.5f * hval + 0.5f * (val + bias[n]);
            }
        }
}

__global__ __launch_bounds__(256) void k_final(const float* __restrict__ x,
        const float* __restrict__ resid, float* __restrict__ out) {
    int gid = blockIdx.x * 256 + threadIdx.x;
    float4 xv = ((const float4*)x)[gid];
    float4 rv = ((const float4*)resid)[gid];
    float4 o;
    o.x = xv.x - rv.x; o.y = xv.y - rv.y; o.z = xv.z - rv.z; o.w = xv.w - rv.w;
    ((float4*)out)[gid] = o;
}

extern "C" void kernel_launch(void* const* d_in, const int* in_sizes, int n_in,
                              void* d_out, int out_size, void* d_ws, size_t ws_size,
                              hipStream_t stream) {
    const float* x     = (const float*)d_in[0];
    const float* embed = (const float*)d_in[1];
    const float* pw    = (const float*)d_in[2];
    const float* pb    = (const float*)d_in[3];
    float* out = (float*)d_out;

    // ws layout (floats), ~54.6 MB:
    // resid 16MB | U 16MB (zh/zl, then u for s<=128 OR hh/hl for s>=256) |
    // ehi/elo 8MB | Wt2 hi/lo 12MB | esq | minbuf
    float* resid = (float*)d_ws;
    float* Ubase = resid + 4194304;
    _Float16* zh = (_Float16*)Ubase;
    _Float16* zl = zh + 4194304;
    float* u = Ubase;
    _Float16* hh = (_Float16*)Ubase;
    _Float16* hl = hh + 4194304;
    _Float16* ehi = (_Float16*)(Ubase + 4194304);
    _Float16* elo = ehi + 2097152;
    _Float16* whi = elo + 2097152;
    _Float16* wlo = whi + 3145728;
    float* esq = (float*)(wlo + 3145728);
    unsigned long long* minbuf = (unsigned long long*)(esq + 4096);

    k_esq<<<1024, 256, 0, stream>>>(embed, esq);
    k_split_embed<<<2048, 256, 0, stream>>>(embed, ehi, elo);
    k_split_w<<<12288, 256, 0, stream>>>(pw, whi, wlo);
    k_copy<<<4096, 256, 0, stream>>>(x, resid);

    const int SCv[10] = {1, 2, 4, 8, 16, 32, 64, 128, 256, 512};
    // PHI_IDX with float64-ulp tie-breaks at si=2 and si=7 (verified round 2)
    const int PIv[10] = {0, 0, 1, 1, 1, 2, 2, 3, 3, 3};
    for (int si = 0; si < 10; ++si) {
        int s = SCv[si];
        int M = 16 * s;
        int kp = PIv[si];
        int lg = __builtin_ctz((unsigned)s);
        float scale = (float)s / 512.0f;
        k_zmean<<<(M * 512) / 256, 256, 0, stream>>>(resid, zh, zl, minbuf, s, lg);
        k_dist_mfma<<<dim3((M + 127) / 128, 32), 256, 0, stream>>>(zh, zl, ehi, elo, esq, minbuf, M);
        if (s <= 128) {
            k_phi<<<dim3((M + 127) / 128, 12), 256, 0, stream>>>(ehi, elo,
                    whi + (size_t)kp * 1536 * 512, wlo + (size_t)kp * 1536 * 512, minbuf, u, M);
            k_combine<<<4096, 256, 0, stream>>>(u, embed, minbuf, pb + kp * 512, resid, s, scale);
        } else {
            k_hsplit<<<2048, 256, 0, stream>>>(minbuf, embed, hh, hl, s, scale);
            k_conv<<<dim3(64, 4), 256, 0, stream>>>(hh, hl,
                    whi + (size_t)kp * 1536 * 512, wlo + (size_t)kp * 1536 * 512,
                    pb + kp * 512, resid);
        }
    }
    k_final<<<4096, 256, 0, stream>>>(x, resid, out);
}

// Round 8
// 1176.812 us; speedup vs baseline: 1.6534x; 1.6534x over previous
//
#include <hip/hip_runtime.h>

// Multiscale Residual VQ (VAR-style), MI355X gfx950.
// Round 8: round-5 barrier structure (load -> LDS-write immediately, regs die
// before the barrier; proven no-spill) + round-6/7 fragment-slot LDS layout
// (lane*16 ds ops -> 2-way -> conflict-free). Round 7's extra barrier between
// load and write extended staging-reg live ranges across the barrier -> 577MB
// scratch spills (WRITE_SIZE counter) -> 2x regression. This removes it.
// All MFMA dots bit-identical to rounds 4-7 -> zero argmin-flip risk.

#define ND 512
#define NCB 4096

typedef _Float16 half8v __attribute__((ext_vector_type(8)));
typedef float floatx4 __attribute__((ext_vector_type(4)));

struct HL { _Float16 h, l; };

__device__ __forceinline__ HL split2(float v) {
    HL r;
    r.h = (_Float16)v;
    r.l = (_Float16)((v - (float)r.h) * 4096.0f);
    return r;
}

__device__ __forceinline__ unsigned long long pack_dist(float d, int n) {
    unsigned u = __float_as_uint(d);
    u = (u & 0x80000000u) ? ~u : (u | 0x80000000u);   // monotone total order
    return ((unsigned long long)u << 32) | (unsigned)n; // tie -> lowest idx
}

// e_sq[c] = sum_d embed[c,d]^2, fp64 accumulate
__global__ __launch_bounds__(256) void k_esq(const float* __restrict__ embed,
                                             float* __restrict__ esq) {
    int c = blockIdx.x * 4 + (threadIdx.x >> 6);
    int lane = threadIdx.x & 63;
    const float* row = embed + (size_t)c * ND;
    double acc = 0.0;
#pragma unroll
    for (int i = 0; i < ND / 64; ++i) {
        float v = row[lane + i * 64];
        acc += (double)v * (double)v;
    }
#pragma unroll
    for (int off = 32; off > 0; off >>= 1) acc += __shfl_down(acc, off, 64);
    if (lane == 0) esq[c] = (float)acc;
}

__global__ __launch_bounds__(256) void k_copy(const float* __restrict__ src,
                                              float* __restrict__ dst) {
    int gid = blockIdx.x * 256 + threadIdx.x;
    ((float4*)dst)[gid] = ((const float4*)src)[gid];
}

// embed -> ehi/elo row-major halves (4096x512)
__global__ __launch_bounds__(256) void k_split_embed(const float* __restrict__ embed,
        _Float16* __restrict__ eh, _Float16* __restrict__ el) {
    int gid = blockIdx.x * 256 + threadIdx.x;       // 524288 float4s
    float4 v = ((const float4*)embed)[gid];
    HL a = split2(v.x), b = split2(v.y), c = split2(v.z), d = split2(v.w);
    _Float16* ph = eh + (size_t)gid * 4;
    _Float16* pl = el + (size_t)gid * 4;
    ph[0] = a.h; ph[1] = b.h; ph[2] = c.h; ph[3] = d.h;
    pl[0] = a.l; pl[1] = b.l; pl[2] = c.l; pl[3] = d.l;
}

// Wt2[kp][tap*512+dout][din] hi/lo from pw[kp][dout][din][tap]
__global__ __launch_bounds__(256) void k_split_w(const float* __restrict__ pw,
        _Float16* __restrict__ wh, _Float16* __restrict__ wl) {
    int gid = blockIdx.x * 256 + threadIdx.x;       // 4*1536*512
    int din = gid & 511;
    int nn = (gid >> 9) % 1536;
    int kp = gid / (512 * 1536);
    int tap = nn >> 9;
    int dout = nn & 511;
    float v = pw[(((size_t)(kp * 512 + dout) * 512) + din) * 3 + tap];
    HL r = split2(v);
    wh[gid] = r.h;
    wl[gid] = r.l;
}

// z[b,j,d] = block mean of residual (fp64 acc) -> split zh/zl; also inits minbuf
__global__ __launch_bounds__(256) void k_zmean(const float* __restrict__ resid,
        _Float16* __restrict__ zh, _Float16* __restrict__ zl,
        unsigned long long* __restrict__ minbuf, int s, int lg) {
    int gid = blockIdx.x * 256 + threadIdx.x;       // 16*s*512 threads
    int M = 16 * s;
    if (gid < M) minbuf[gid] = ~0ull;
    int d = gid & 511;
    int j = (gid >> 9) & (s - 1);
    int b = gid >> (9 + lg);
    int r = 512 >> lg;
    const float* p = resid + ((size_t)((b << 9) + (j << (9 - lg))) << 9) + d;
    double acc = 0.0;
#pragma unroll 4
    for (int m = 0; m < r; ++m) acc += (double)p[(size_t)m * ND];
    float v = (float)(acc * (1.0 / (double)r));
    HL hl = split2(v);
    zh[gid] = hl.h;
    zl[gid] = hl.l;
}

// h split: hh/hl[b*512+t][d] = split(lerp of embed rows per half-pixel upsample)
__global__ __launch_bounds__(256) void k_hsplit(const unsigned long long* __restrict__ minbuf,
        const float* __restrict__ embed, _Float16* __restrict__ hh,
        _Float16* __restrict__ hl, int s, float scale) {
    int gid = blockIdx.x * 256 + threadIdx.x;       // 524288: one 8-elem chunk
    int d8 = (gid & 63) << 3;
    int m = gid >> 6;
    int b = m >> 9, t = m & 511;
    float u = ((float)t + 0.5f) * scale - 0.5f;
    float fl = floorf(u);
    float w = u - fl;
    int i0 = (int)fl, i1 = i0 + 1;
    i0 = min(max(i0, 0), s - 1);
    i1 = min(max(i1, 0), s - 1);
    int c0 = (int)(unsigned)minbuf[b * s + i0];
    int c1 = (int)(unsigned)minbuf[b * s + i1];
    const float* p0 = embed + (size_t)c0 * 512 + d8;
    const float* p1 = embed + (size_t)c1 * 512 + d8;
    float om = 1.0f - w;
    half8v vh, vl;
#pragma unroll
    for (int q = 0; q < 8; ++q) {
        HL r = split2(om * p0[q] + w * p1[q]);
        vh[q] = r.h; vl[q] = r.l;
    }
    *(half8v*)(hh + (size_t)m * 512 + d8) = vh;
    *(half8v*)(hl + (size_t)m * 512 + d8) = vl;
}

// ---------------- dist: block 128m x 128n, 4 waves (2x2) each 64x64 ----------------
// LDS: fragment slots [frag = mt*2+half][slotlane*8], 16B per slotlane.
__global__ __launch_bounds__(256, 2) void k_dist_mfma(const _Float16* __restrict__ zh,
        const _Float16* __restrict__ zl, const _Float16* __restrict__ eh,
        const _Float16* __restrict__ el, const float* __restrict__ esq,
        unsigned long long* __restrict__ minbuf, int M) {
    __shared__ _Float16 Asl[16][512];
    __shared__ _Float16 Bsl[16][512];
    __shared__ unsigned long long packs[128][2];
    int tid = threadIdx.x;
    int lane = tid & 63, wave = tid >> 6;
    int wm = wave >> 1, wn = wave & 1;
    int quad = lane >> 4, l15 = lane & 15;
    int m0 = blockIdx.x * 128, n0 = blockIdx.y * 128;

    floatx4 acch[4][4], accx[4][4];
#pragma unroll
    for (int i = 0; i < 4; ++i)
#pragma unroll
        for (int j = 0; j < 4; ++j)
#pragma unroll
            for (int r = 0; r < 4; ++r) { acch[i][j][r] = 0.f; accx[i][j][r] = 0.f; }

    for (int kc = 0; kc < 16; ++kc) {
        int kb = kc * 32;
        // stage: load -> write LDS immediately (regs die before the barrier)
#pragma unroll
        for (int ch = 0; ch < 4; ++ch) {
            int g = tid + ch * 256;
            int fr = g >> 6, sl = g & 63;
            int mt = fr >> 1, half = fr & 1;
            int ko = kb + (sl >> 4) * 8;
            int arow = m0 + mt * 16 + (sl & 15); if (arow >= M) arow = M - 1;
            int4 av = *(const int4*)((half ? zl : zh) + (size_t)arow * 512 + ko);
            int brow = n0 + mt * 16 + (sl & 15);
            int4 bv = *(const int4*)((half ? el : eh) + (size_t)brow * 512 + ko);
            *(int4*)&Asl[fr][sl * 8] = av;
            *(int4*)&Bsl[fr][sl * 8] = bv;
        }
        __syncthreads();
        half8v afh[4], afl[4], bfh[4], bfl[4];
#pragma unroll
        for (int t = 0; t < 4; ++t) {
            afh[t] = *(const half8v*)&Asl[(wm * 4 + t) * 2 + 0][lane * 8];
            afl[t] = *(const half8v*)&Asl[(wm * 4 + t) * 2 + 1][lane * 8];
            bfh[t] = *(const half8v*)&Bsl[(wn * 4 + t) * 2 + 0][lane * 8];
            bfl[t] = *(const half8v*)&Bsl[(wn * 4 + t) * 2 + 1][lane * 8];
        }
#pragma unroll
        for (int tm = 0; tm < 4; ++tm)
#pragma unroll
            for (int tn = 0; tn < 4; ++tn) {
                acch[tm][tn] = __builtin_amdgcn_mfma_f32_16x16x32_f16(afh[tm], bfh[tn], acch[tm][tn], 0, 0, 0);
                accx[tm][tn] = __builtin_amdgcn_mfma_f32_16x16x32_f16(afh[tm], bfl[tn], accx[tm][tn], 0, 0, 0);
                accx[tm][tn] = __builtin_amdgcn_mfma_f32_16x16x32_f16(afl[tm], bfh[tn], accx[tm][tn], 0, 0, 0);
            }
        __syncthreads();
    }
    float es[4];
#pragma unroll
    for (int tn = 0; tn < 4; ++tn) es[tn] = esq[n0 + wn * 64 + tn * 16 + l15];
#pragma unroll
    for (int tm = 0; tm < 4; ++tm)
#pragma unroll
        for (int reg = 0; reg < 4; ++reg) {
            unsigned long long best = ~0ull;
#pragma unroll
            for (int tn = 0; tn < 4; ++tn) {
                float dot = acch[tm][tn][reg] + accx[tm][tn][reg] * (1.0f / 4096.0f);
                int n = n0 + wn * 64 + tn * 16 + l15;
                float dd = fmaf(-2.f, dot, es[tn]);
                unsigned long long p = pack_dist(dd, n);
                best = p < best ? p : best;
            }
#pragma unroll
            for (int off = 1; off < 16; off <<= 1) {
                unsigned long long q = __shfl_xor(best, off, 64);
                best = q < best ? q : best;
            }
            if (l15 == 0) packs[wm * 64 + tm * 16 + quad * 4 + reg][wn] = best;
        }
    __syncthreads();
    if (tid < 128 && m0 + tid < M) {
        unsigned long long b0 = packs[tid][0], b1 = packs[tid][1];
        atomicMin(&minbuf[m0 + tid], b0 < b1 ? b0 : b1);
    }
}

// ---------------- phi: u[m][tap*512+dout] = (W_tap q_m)[dout] ----------------
__global__ __launch_bounds__(256, 2) void k_phi(const _Float16* __restrict__ eh,
        const _Float16* __restrict__ el, const _Float16* __restrict__ wh,
        const _Float16* __restrict__ wl, const unsigned long long* __restrict__ minbuf,
        float* __restrict__ u, int M) {
    __shared__ _Float16 Asl[16][512];
    __shared__ _Float16 Bsl[16][512];
    __shared__ int idxs[128];
    int tid = threadIdx.x;
    int lane = tid & 63, wave = tid >> 6;
    int wm = wave >> 1, wn = wave & 1;
    int quad = lane >> 4, l15 = lane & 15;
    int m0 = blockIdx.x * 128, n0 = blockIdx.y * 128;
    if (tid < 128) {
        int m = m0 + tid; if (m >= M) m = M - 1;
        idxs[tid] = (int)(unsigned)minbuf[m];
    }
    floatx4 acch[4][4], accx[4][4];
#pragma unroll
    for (int i = 0; i < 4; ++i)
#pragma unroll
        for (int j = 0; j < 4; ++j)
#pragma unroll
            for (int r = 0; r < 4; ++r) { acch[i][j][r] = 0.f; accx[i][j][r] = 0.f; }
    __syncthreads();
    for (int kc = 0; kc < 16; ++kc) {
        int kb = kc * 32;
#pragma unroll
        for (int ch = 0; ch < 4; ++ch) {
            int g = tid + ch * 256;
            int fr = g >> 6, sl = g & 63;
            int mt = fr >> 1, half = fr & 1;
            int ko = kb + (sl >> 4) * 8;
            int code = idxs[mt * 16 + (sl & 15)];
            int4 av = *(const int4*)((half ? el : eh) + (size_t)code * 512 + ko);
            int brow = n0 + mt * 16 + (sl & 15);
            int4 bv = *(const int4*)((half ? wl : wh) + (size_t)brow * 512 + ko);
            *(int4*)&Asl[fr][sl * 8] = av;
            *(int4*)&Bsl[fr][sl * 8] = bv;
        }
        __syncthreads();
        half8v afh[4], afl[4], bfh[4], bfl[4];
#pragma unroll
        for (int t = 0; t < 4; ++t) {
            afh[t] = *(const half8v*)&Asl[(wm * 4 + t) * 2 + 0][lane * 8];
            afl[t] = *(const half8v*)&Asl[(wm * 4 + t) * 2 + 1][lane * 8];
            bfh[t] = *(const half8v*)&Bsl[(wn * 4 + t) * 2 + 0][lane * 8];
            bfl[t] = *(const half8v*)&Bsl[(wn * 4 + t) * 2 + 1][lane * 8];
        }
#pragma unroll
        for (int tm = 0; tm < 4; ++tm)
#pragma unroll
            for (int tn = 0; tn < 4; ++tn) {
                acch[tm][tn] = __builtin_amdgcn_mfma_f32_16x16x32_f16(afh[tm], bfh[tn], acch[tm][tn], 0, 0, 0);
                accx[tm][tn] = __builtin_amdgcn_mfma_f32_16x16x32_f16(afh[tm], bfl[tn], accx[tm][tn], 0, 0, 0);
                accx[tm][tn] = __builtin_amdgcn_mfma_f32_16x16x32_f16(afl[tm], bfh[tn], accx[tm][tn], 0, 0, 0);
            }
        __syncthreads();
    }
#pragma unroll
    for (int tm = 0; tm < 4; ++tm)
#pragma unroll
        for (int reg = 0; reg < 4; ++reg) {
            int m = m0 + wm * 64 + tm * 16 + quad * 4 + reg;
            if (m < M) {
#pragma unroll
                for (int tn = 0; tn < 4; ++tn) {
                    int n = n0 + wn * 64 + tn * 16 + l15;
                    u[(size_t)m * 1536 + n] = acch[tm][tn][reg] + accx[tm][tn][reg] * (1.0f / 4096.0f);
                }
            }
        }
}

// combine (s<=128): resid -= 0.5*h + 0.5*(conv+bias); conv[t] = sum_tap lerp of u
__global__ __launch_bounds__(256) void k_combine(const float* __restrict__ u,
        const float* __restrict__ embed, const unsigned long long* __restrict__ minbuf,
        const float* __restrict__ bias, float* __restrict__ resid, int s, float scale) {
    int tid = threadIdx.x;
    int m = blockIdx.x * 2 + (tid >> 7);
    int d4 = (tid & 127) << 2;
    int b = m >> 9, t = m & 511;
    int bs = b * s;
    float4 bi = *(const float4*)(bias + d4);
    float uu = ((float)t + 0.5f) * scale - 0.5f;
    float fl = floorf(uu);
    float w = uu - fl;
    int i0 = (int)fl, i1 = i0 + 1;
    i0 = min(max(i0, 0), s - 1);
    i1 = min(max(i1, 0), s - 1);
    int c0 = (int)(unsigned)minbuf[bs + i0];
    int c1 = (int)(unsigned)minbuf[bs + i1];
    float4 e0 = *(const float4*)(embed + (size_t)c0 * 512 + d4);
    float4 e1 = *(const float4*)(embed + (size_t)c1 * 512 + d4);
    float om = 1.0f - w;
    float4 h4;
    h4.x = om * e0.x + w * e1.x; h4.y = om * e0.y + w * e1.y;
    h4.z = om * e0.z + w * e1.z; h4.w = om * e0.w + w * e1.w;
    float4 conv = make_float4(0.f, 0.f, 0.f, 0.f);
#pragma unroll
    for (int tap = 0; tap < 3; ++tap) {
        int tt = t + tap - 1;
        if (tt >= 0 && tt < 512) {
            float uu2 = ((float)tt + 0.5f) * scale - 0.5f;
            float fl2 = floorf(uu2);
            float w2 = uu2 - fl2;
            int j0 = (int)fl2, j1 = j0 + 1;
            j0 = min(max(j0, 0), s - 1);
            j1 = min(max(j1, 0), s - 1);
            float4 a4 = *(const float4*)(u + (size_t)(bs + j0) * 1536 + tap * 512 + d4);
            float4 b4 = *(const float4*)(u + (size_t)(bs + j1) * 1536 + tap * 512 + d4);
            float ow = 1.0f - w2;
            conv.x += ow * a4.x + w2 * b4.x;
            conv.y += ow * a4.y + w2 * b4.y;
            conv.z += ow * a4.z + w2 * b4.z;
            conv.w += ow * a4.w + w2 * b4.w;
        }
    }
    size_t off = (size_t)m * 512 + d4;
    float4 rv = *(float4*)(resid + off);
    rv.x -= 0.5f * h4.x + 0.5f * (conv.x + bi.x);
    rv.y -= 0.5f * h4.y + 0.5f * (conv.y + bi.y);
    rv.z -= 0.5f * h4.z + 0.5f * (conv.z + bi.z);
    rv.w -= 0.5f * h4.w + 0.5f * (conv.w + bi.w);
    *(float4*)(resid + off) = rv;
}

// direct conv (s in {256,512}): A = hsplit rows shifted by tap, B = Wt2.
// epilogue: resid -= 0.5*h + 0.5*(conv+bias). grid(64, 4)
__global__ __launch_bounds__(256, 2) void k_conv(const _Float16* __restrict__ hh,
        const _Float16* __restrict__ hl, const _Float16* __restrict__ wh,
        const _Float16* __restrict__ wl, const float* __restrict__ bias,
        float* __restrict__ resid) {
    __shared__ _Float16 Asl[16][512];
    __shared__ _Float16 Bsl[16][512];
    int tid = threadIdx.x;
    int lane = tid & 63, wave = tid >> 6;
    int wm = wave >> 1, wn = wave & 1;
    int quad = lane >> 4, l15 = lane & 15;
    int m0 = blockIdx.x * 128, n0 = blockIdx.y * 128;
    int bb = m0 >> 9, t0 = m0 & 511;

    floatx4 acch[4][4], accx[4][4];
#pragma unroll
    for (int i = 0; i < 4; ++i)
#pragma unroll
        for (int j = 0; j < 4; ++j)
#pragma unroll
            for (int r = 0; r < 4; ++r) { acch[i][j][r] = 0.f; accx[i][j][r] = 0.f; }

    for (int kc = 0; kc < 48; ++kc) {
        int tap = kc >> 4;
        int kbd = (kc & 15) * 32;
#pragma unroll
        for (int ch = 0; ch < 4; ++ch) {
            int g = tid + ch * 256;
            int fr = g >> 6, sl = g & 63;
            int mt = fr >> 1, half = fr & 1;
            int ko = kbd + (sl >> 4) * 8;
            int tt = t0 + mt * 16 + (sl & 15) + tap - 1;
            int4 av = make_int4(0, 0, 0, 0);
            if ((unsigned)tt < 512u)
                av = *(const int4*)((half ? hl : hh) + ((size_t)((bb << 9) + tt)) * 512 + ko);
            int brow = tap * 512 + n0 + mt * 16 + (sl & 15);
            int4 bv = *(const int4*)((half ? wl : wh) + (size_t)brow * 512 + ko);
            *(int4*)&Asl[fr][sl * 8] = av;
            *(int4*)&Bsl[fr][sl * 8] = bv;
        }
        __syncthreads();
        half8v afh[4], afl[4], bfh[4], bfl[4];
#pragma unroll
        for (int t = 0; t < 4; ++t) {
            afh[t] = *(const half8v*)&Asl[(wm * 4 + t) * 2 + 0][lane * 8];
            afl[t] = *(const half8v*)&Asl[(wm * 4 + t) * 2 + 1][lane * 8];
            bfh[t] = *(const half8v*)&Bsl[(wn * 4 + t) * 2 + 0][lane * 8];
            bfl[t] = *(const half8v*)&Bsl[(wn * 4 + t) * 2 + 1][lane * 8];
        }
#pragma unroll
        for (int tm = 0; tm < 4; ++tm)
#pragma unroll
            for (int tn = 0; tn < 4; ++tn) {
                acch[tm][tn] = __builtin_amdgcn_mfma_f32_16x16x32_f16(afh[tm], bfh[tn], acch[tm][tn], 0, 0, 0);
                accx[tm][tn] = __builtin_amdgcn_mfma_f32_16x16x32_f16(afh[tm], bfl[tn], accx[tm][tn], 0, 0, 0);
                accx[tm][tn] = __builtin_amdgcn_mfma_f32_16x16x32_f16(afl[tm], bfh[tn], accx[tm][tn], 0, 0, 0);
            }
        __syncthreads();
    }
#pragma unroll
    for (int tm = 0; tm < 4; ++tm)
#pragma unroll
        for (int reg = 0; reg < 4; ++reg) {
            int m = m0 + wm * 64 + tm * 16 + quad * 4 + reg;
#pragma unroll
            for (int tn = 0; tn < 4; ++tn) {
                int n = n0 + wn * 64 + tn * 16 + l15;
                size_t off = (size_t)m * 512 + n;
                float hval = (float)hh[off] + (float)hl[off] * (1.0f / 4096.0f);
                float val = acch[tm][tn][reg] + accx[tm][tn][reg] * (1.0f / 4096.0f);
                resid[off] -= 0.5f * hval + 0.5f * (val + bias[n]);
            }
        }
}

__global__ __launch_bounds__(256) void k_final(const float* __restrict__ x,
        const float* __restrict__ resid, float* __restrict__ out) {
    int gid = blockIdx.x * 256 + threadIdx.x;
    float4 xv = ((const float4*)x)[gid];
    float4 rv = ((const float4*)resid)[gid];
    float4 o;
    o.x = xv.x - rv.x; o.y = xv.y - rv.y; o.z = xv.z - rv.z; o.w = xv.w - rv.w;
    ((float4*)out)[gid] = o;
}

extern "C" void kernel_launch(void* const* d_in, const int* in_sizes, int n_in,
                              void* d_out, int out_size, void* d_ws, size_t ws_size,
                              hipStream_t stream) {
    const float* x     = (const float*)d_in[0];
    const float* embed = (const float*)d_in[1];
    const float* pw    = (const float*)d_in[2];
    const float* pb    = (const float*)d_in[3];
    float* out = (float*)d_out;

    // ws layout (floats), ~54.6 MB:
    // resid 16MB | U 16MB (zh/zl, then u for s<=128 OR hh/hl for s>=256) |
    // ehi/elo 8MB | Wt2 hi/lo 12MB | esq | minbuf
    float* resid = (float*)d_ws;
    float* Ubase = resid + 4194304;
    _Float16* zh = (_Float16*)Ubase;
    _Float16* zl = zh + 4194304;
    float* u = Ubase;
    _Float16* hh = (_Float16*)Ubase;
    _Float16* hl = hh + 4194304;
    _Float16* ehi = (_Float16*)(Ubase + 4194304);
    _Float16* elo = ehi + 2097152;
    _Float16* whi = elo + 2097152;
    _Float16* wlo = whi + 3145728;
    float* esq = (float*)(wlo + 3145728);
    unsigned long long* minbuf = (unsigned long long*)(esq + 4096);

    k_esq<<<1024, 256, 0, stream>>>(embed, esq);
    k_split_embed<<<2048, 256, 0, stream>>>(embed, ehi, elo);
    k_split_w<<<12288, 256, 0, stream>>>(pw, whi, wlo);
    k_copy<<<4096, 256, 0, stream>>>(x, resid);

    const int SCv[10] = {1, 2, 4, 8, 16, 32, 64, 128, 256, 512};
    // PHI_IDX with float64-ulp tie-breaks at si=2 and si=7 (verified round 2)
    const int PIv[10] = {0, 0, 1, 1, 1, 2, 2, 3, 3, 3};
    for (int si = 0; si < 10; ++si) {
        int s = SCv[si];
        int M = 16 * s;
        int kp = PIv[si];
        int lg = __builtin_ctz((unsigned)s);
        float scale = (float)s / 512.0f;
        k_zmean<<<(M * 512) / 256, 256, 0, stream>>>(resid, zh, zl, minbuf, s, lg);
        k_dist_mfma<<<dim3((M + 127) / 128, 32), 256, 0, stream>>>(zh, zl, ehi, elo, esq, minbuf, M);
        if (s <= 128) {
            k_phi<<<dim3((M + 127) / 128, 12), 256, 0, stream>>>(ehi, elo,
                    whi + (size_t)kp * 1536 * 512, wlo + (size_t)kp * 1536 * 512, minbuf, u, M);
            k_combine<<<4096, 256, 0, stream>>>(u, embed, minbuf, pb + kp * 512, resid, s, scale);
        } else {
            k_hsplit<<<2048, 256, 0, stream>>>(minbuf, embed, hh, hl, s, scale);
            k_conv<<<dim3(64, 4), 256, 0, stream>>>(hh, hl,
                    whi + (size_t)kp * 1536 * 512, wlo + (size_t)kp * 1536 * 512,
                    pb + kp * 512, resid);
        }
    }
    k_final<<<4096, 256, 0, stream>>>(x, resid, out);
}